// Round 8
// baseline (228.571 us; speedup 1.0000x reference)
//
#include <hip/hip_runtime.h>
#include <cstdint>
#include <cstddef>

#define SEQ 4096
#define DH 2048
#define DOUT 1024

typedef float f32x4 __attribute__((ext_vector_type(4)));
typedef __bf16 bf16x8 __attribute__((ext_vector_type(8)));
typedef long longx2 __attribute__((ext_vector_type(2)));

// ---- helpers --------------------------------------------------------------

__device__ __forceinline__ unsigned short f2bf(float f) {
  // round-to-nearest-even fp32 -> bf16 (inputs are finite; no NaN handling)
  unsigned int u = __float_as_uint(f);
  unsigned int r = (u + 0x7FFFu + ((u >> 16) & 1u)) >> 16;
  return (unsigned short)r;
}

// fp32 -> OCP e4m3fn, RNE, saturate. Software fallback (used only if the HW
// builtin is unavailable).
__device__ __forceinline__ unsigned char f2f8_sw(float f) {
  unsigned int u = __float_as_uint(f);
  unsigned int sign = (u >> 24) & 0x80u;
  float a = __uint_as_float(u & 0x7FFFFFFFu);
  if (a >= 448.f) return (unsigned char)(sign | 0x7Eu);
  if (a < 0.015625f) {
    int q = (int)rintf(a * 512.0f);
    if (q == 8) return (unsigned char)(sign | 0x08u);
    return (unsigned char)(sign | (unsigned)q);
  }
  int e = (int)((u >> 23) & 0xFF) - 127;
  unsigned int m = u & 0x7FFFFFu;
  unsigned int m3 = (m + 0x7FFFFu + ((m >> 20) & 1u)) >> 20;
  if (m3 == 8u) { m3 = 0u; e++; if (e > 8) return (unsigned char)(sign | 0x7Eu); }
  return (unsigned char)(sign | ((unsigned)(e + 7) << 3) | m3);
}

// pack 4 fp32 -> 4 fp8 bytes. HW path: 2x v_cvt_pk_fp8_f32.
__device__ __forceinline__ unsigned int pk4_f8(float a, float b, float c, float d) {
#if __has_builtin(__builtin_amdgcn_cvt_pk_fp8_f32)
  int r = __builtin_amdgcn_cvt_pk_fp8_f32(a, b, 0, false);   // low word
  r = __builtin_amdgcn_cvt_pk_fp8_f32(c, d, r, true);        // high word
  return (unsigned int)r;
#else
  return (unsigned)f2f8_sw(a) | ((unsigned)f2f8_sw(b) << 8) |
         ((unsigned)f2f8_sw(c) << 16) | ((unsigned)f2f8_sw(d) << 24);
#endif
}

__device__ __forceinline__ void g2l16(const void* g, void* l) {
  // async global -> LDS, 16 bytes per lane. LDS side is wave-uniform base + lane*16.
  __builtin_amdgcn_global_load_lds((__attribute__((address_space(1))) void*)g,
                                   (__attribute__((address_space(3))) void*)l, 16, 0, 0);
}

#define W_SCALE 1048576.0f         // 2^20: lifts w (~2.4e-7) into e4m3 range
#define W_SCALE_INV (1.0f / 1048576.0f)

// ---- kernel 1: per-row mean / rstd of gate half ---------------------------

__global__ __launch_bounds__(256) void ln_stats(const float* __restrict__ x,
                                                float* __restrict__ mv,
                                                float* __restrict__ rv) {
  int row = blockIdx.x;
  const float4* g4 = (const float4*)(x + (size_t)row * (2 * DH) + DH);
  float4 a = g4[threadIdx.x];
  float4 b = g4[threadIdx.x + 256];
  float s  = a.x + a.y + a.z + a.w + b.x + b.y + b.z + b.w;
  float s2 = a.x * a.x + a.y * a.y + a.z * a.z + a.w * a.w +
             b.x * b.x + b.y * b.y + b.z * b.z + b.w * b.w;
#pragma unroll
  for (int o = 32; o > 0; o >>= 1) {
    s  += __shfl_down(s, o);
    s2 += __shfl_down(s2, o);
  }
  __shared__ float red[8];
  int wave = threadIdx.x >> 6;
  if ((threadIdx.x & 63) == 0) { red[wave] = s; red[wave + 4] = s2; }
  __syncthreads();
  if (threadIdx.x == 0) {
    float S  = red[0] + red[1] + red[2] + red[3];
    float S2 = red[4] + red[5] + red[6] + red[7];
    float mean = S * (1.0f / DH);
    float var  = S2 * (1.0f / DH) - mean * mean;  // ddof=0, matches jnp.var
    mv[row] = mean;
    rv[row] = rsqrtf(var + 1e-5f);
  }
}

// ---- kernel 2: fused prep (independent sections co-fill the machine) ------
// blocks [0,2048):        norm+transpose+fp8 -> gf8T[d][n]
// blocks [2048,6144):     w -> fp8 tril cast (x 2^20), 16 elems/thread
// blocks [6144,6656):     proj_w transpose+cast -> projT[j][d] bf16

__global__ __launch_bounds__(256) void prep2(const float* __restrict__ x,
                                             const float* __restrict__ mv,
                                             const float* __restrict__ rv,
                                             const float* __restrict__ lns,
                                             unsigned char* __restrict__ gf8T,
                                             const float* __restrict__ w,
                                             unsigned char* __restrict__ wf8,
                                             const float* __restrict__ pw,
                                             unsigned short* __restrict__ pT) {
  int b = blockIdx.x;
  if (b < 2048) {
    // ---- normalize + scale + transpose + fp8 ----
    __shared__ float tile[64][65];  // +1 pad
    int d0 = (b & 31) * 64;         // d-tile (0..2047)
    int n0 = (b >> 5) * 64;         // n-tile (0..4095)
#pragma unroll
    for (int i = 0; i < 16; i++) {
      int idx = threadIdx.x + i * 256;
      int r = idx >> 6, c = idx & 63;  // r = n offset, c = d offset (coalesced in c)
      float v = x[(size_t)(n0 + r) * (2 * DH) + DH + d0 + c];
      tile[r][c] = (v - mv[n0 + r]) * rv[n0 + r];
    }
    __syncthreads();
#pragma unroll
    for (int i = 0; i < 4; i++) {
      int idx = threadIdx.x + i * 256;   // [0,1024)
      int dr = idx >> 4;                 // d offset (0..63)
      int nq = idx & 15;                 // n quad (0..15)
      float sc = lns[d0 + dr];
      unsigned int pk = pk4_f8(tile[nq * 4 + 0][dr] * sc, tile[nq * 4 + 1][dr] * sc,
                               tile[nq * 4 + 2][dr] * sc, tile[nq * 4 + 3][dr] * sc);
      *(unsigned int*)&gf8T[(size_t)(d0 + dr) * SEQ + n0 + nq * 4] = pk;
    }
  } else if (b < 6144) {
    // ---- tril-masked w -> fp8 (x 2^20) ----
    size_t e = (((size_t)(b - 2048)) * 256 + threadIdx.x) * 16;
    int m = (int)(e >> 12);    // row (4096 cols)
    int k = (int)(e & 4095);   // col (16-aligned)
    uint4 o;
    if (k > m) {               // fully above diagonal: zeros, no read
      o.x = o.y = o.z = o.w = 0u;
    } else {
      const float4* s4 = (const float4*)(w + e);
      float4 v0 = s4[0], v1 = s4[1], v2 = s4[2], v3 = s4[3];
      float vv[16] = {v0.x, v0.y, v0.z, v0.w, v1.x, v1.y, v1.z, v1.w,
                      v2.x, v2.y, v2.z, v2.w, v3.x, v3.y, v3.z, v3.w};
      if (k + 15 > m) {        // straddles diagonal: zero-mask above
#pragma unroll
        for (int j = 0; j < 16; j++) vv[j] = (k + j <= m) ? vv[j] : 0.0f;
      }
      o.x = pk4_f8(vv[0] * W_SCALE, vv[1] * W_SCALE, vv[2] * W_SCALE, vv[3] * W_SCALE);
      o.y = pk4_f8(vv[4] * W_SCALE, vv[5] * W_SCALE, vv[6] * W_SCALE, vv[7] * W_SCALE);
      o.z = pk4_f8(vv[8] * W_SCALE, vv[9] * W_SCALE, vv[10] * W_SCALE, vv[11] * W_SCALE);
      o.w = pk4_f8(vv[12] * W_SCALE, vv[13] * W_SCALE, vv[14] * W_SCALE, vv[15] * W_SCALE);
    }
    *(uint4*)(wf8 + e) = o;
  } else {
    // ---- proj_w transpose+cast -> projT[j][d] bf16 ----
    __shared__ float tile[64][65];
    int b2 = b - 6144;                 // [0,512)
    int j0 = (b2 & 15) * 64;           // out-col tile (0..1023)
    int d0 = (b2 >> 4) * 64;           // d tile (0..2047)
#pragma unroll
    for (int i = 0; i < 16; i++) {
      int idx = threadIdx.x + i * 256;
      int r = idx >> 6, c = idx & 63;  // r = d offset, c = j offset
      tile[r][c] = pw[(size_t)(d0 + r) * DOUT + j0 + c];
    }
    __syncthreads();
#pragma unroll
    for (int i = 0; i < 16; i++) {
      int idx = threadIdx.x + i * 256;
      int jr = idx >> 6, dc = idx & 63;
      pT[(size_t)(j0 + jr) * DH + d0 + dc] = f2bf(tile[dc][jr]);
    }
  }
}

// ---- GEMM1: fp8 MFMA, 64x64 tile, BK=128, counted-vmcnt 2-deep pipeline ---
// At the m97-structure ceiling (716 TF eff, 34% of fp8 ubench) — frozen
// except T5 setprio around the MFMA cluster (independent-blocks regime:
// 4 blocks/CU at different phases, the m191 +4-7% case, not m190's
// lockstep null).

__global__ __launch_bounds__(256) void gemm_f8(const unsigned char* __restrict__ A,
                                               const unsigned char* __restrict__ BT,
                                               const float* __restrict__ xfull,
                                               const float* __restrict__ rbias,
                                               unsigned short* __restrict__ Pout) {
  constexpr int BK = 128;
  constexpr int ASZ = 64 * BK;   // 8 KB
  __shared__ unsigned char sA[2 * ASZ];
  __shared__ unsigned char sB[2 * ASZ];

  const int tid = threadIdx.x;
  const int lane = tid & 63, wave = tid >> 6;
  const int quad = lane >> 4, l16 = lane & 15;
  const int wm = wave >> 1, wn = wave & 1;
  const int K = SEQ;

  const int lin = blockIdx.x;
  const int sw = ((lin & 7) << 7) | (lin >> 3);  // chunked XCD swizzle
  const int bn0 = (sw >> 5) * 64;                // d-tile, confined per XCD
  const int by0 = sw & 31;                       // m-pair id

  for (int pass = 0; pass < 2; pass++) {
    const int by = pass == 0 ? by0 : 63 - by0;
    const int bm0 = by * 64;
    const int nt = (by + 2) >> 1;   // ceil(64*(by+1)/128); pair sums to 33

    const unsigned char* aP[2];
    const unsigned char* bP[2];
#pragma unroll
    for (int r = 0; r < 2; r++) {
      int idx = r * 256 + tid;
      int row = idx >> 3;
      int col = ((idx & 7) ^ (row & 7)) * 16;
      aP[r] = A + (size_t)(bm0 + row) * K + col;
      bP[r] = BT + (size_t)(bn0 + row) * K + col;
    }

    f32x4 acc[2][2] = {};

    auto stage = [&](int buf) {
#pragma unroll
      for (int r = 0; r < 2; r++) {
        g2l16(aP[r], &sA[buf * ASZ + (r * 256 + tid) * 16]);
        aP[r] += BK;
      }
#pragma unroll
      for (int r = 0; r < 2; r++) {
        g2l16(bP[r], &sB[buf * ASZ + (r * 256 + tid) * 16]);
        bP[r] += BK;
      }
    };

    auto compute = [&](int buf) {
      const unsigned char* bA = &sA[buf * ASZ];
      const unsigned char* bB = &sB[buf * ASZ];
      long a8[4][2], b8[4][2];
#pragma unroll
      for (int i = 0; i < 2; i++) {
        int R = wm * 32 + i * 16 + l16;
        const unsigned char* rowp = &bA[R * BK];
        int s = R & 7;
        longx2 X = *(const longx2*)&rowp[(quad ^ s) * 16];
        longx2 Y = *(const longx2*)&rowp[((quad + 4) ^ s) * 16];
        a8[0][i] = X[0]; a8[1][i] = X[1]; a8[2][i] = Y[0]; a8[3][i] = Y[1];
      }
#pragma unroll
      for (int j = 0; j < 2; j++) {
        int R = wn * 32 + j * 16 + l16;
        const unsigned char* rowp = &bB[R * BK];
        int s = R & 7;
        longx2 X = *(const longx2*)&rowp[(quad ^ s) * 16];
        longx2 Y = *(const longx2*)&rowp[((quad + 4) ^ s) * 16];
        b8[0][j] = X[0]; b8[1][j] = X[1]; b8[2][j] = Y[0]; b8[3][j] = Y[1];
      }
      __builtin_amdgcn_s_setprio(1);
#pragma unroll
      for (int h = 0; h < 4; h++)
#pragma unroll
        for (int i = 0; i < 2; i++)
#pragma unroll
          for (int j = 0; j < 2; j++)
            acc[i][j] = __builtin_amdgcn_mfma_f32_16x16x32_fp8_fp8(a8[h][i], b8[h][j], acc[i][j], 0, 0, 0);
      __builtin_amdgcn_s_setprio(0);
    };

    stage(0);
    int cur = 0;
    for (int t = 0; t < nt; t++) {
      if (t + 1 < nt) {
        stage(cur ^ 1);
        asm volatile("s_waitcnt vmcnt(4)" ::: "memory");
      } else {
        asm volatile("s_waitcnt vmcnt(0)" ::: "memory");
      }
      __builtin_amdgcn_s_barrier();   // buf `cur` fully staged
      compute(cur);
      __builtin_amdgcn_s_barrier();   // all waves done reading buf `cur`
      cur ^= 1;
    }

    // epilogue — C/D layout: col = lane&15, row = quad*4 + reg (m89-verified)
#pragma unroll
    for (int i = 0; i < 2; i++) {
#pragma unroll
      for (int j = 0; j < 2; j++) {
        int col = bn0 + wn * 32 + j * 16 + l16;
#pragma unroll
        for (int r = 0; r < 4; r++) {
          int row = bm0 + wm * 32 + i * 16 + quad * 4 + r;
          float g = acc[i][j][r] * W_SCALE_INV + rbias[row];
          float pv = xfull[(size_t)row * (2 * DH) + col] * g;
          Pout[(size_t)row * DH + col] = f2bf(pv);
        }
      }
    }
  }
}

// ---- GEMM2: bf16 MFMA, 128x64 tile, BK=64, counted-vmcnt ------------------
// ROUND-7 ANALYSIS: G2 at 64^2 ran ~374 TF, below its structure ceiling;
// LDS floor drops 23.4 -> 17.6us at 128x64 (72KB per block-K-step x 16384
// steps) with a better MFMA:ds_read ratio (16:12 vs 8:8). The R1/R3 failures
// at 2 blocks/CU were FULL-DRAIN barriers; the counted-vmcnt pipeline keeps
// stage loads in flight across the barrier, so 2/CU no longer exposes the
// drain. 512 blocks (2/CU; LDS 48KB dbuf allows 3/CU so no residency cliff),
// 32 uniform k-steps, 6 loads/stage -> vmcnt(6).
// out stays bf16 inputs / fp32 out (feeds the final result; fp8 unsafe).

__global__ __launch_bounds__(256) void gemm_bf(const unsigned short* __restrict__ A,
                                               const unsigned short* __restrict__ BT,
                                               const float* __restrict__ cbias,
                                               float* __restrict__ out,
                                               int N, int K) {
  constexpr int BM = 128, BN = 64, BK = 64;
  constexpr int ASZ = BM * BK;   // 8192 elems = 16 KB
  constexpr int BSZ = BN * BK;   // 4096 elems =  8 KB
  __shared__ unsigned short sA[2 * ASZ];
  __shared__ unsigned short sB[2 * BSZ];

  const int tid = threadIdx.x;
  const int lane = tid & 63, wave = tid >> 6;
  const int quad = lane >> 4, l16 = lane & 15;
  const int wm = wave >> 1, wn = wave & 1;

  const int lin = blockIdx.x;                    // 512 blocks
  const int sw = ((lin & 7) << 6) | (lin >> 3);  // chunked XCD swizzle (64/XCD)
  const int bn0 = (sw & 15) * 64;                // 16 n-tiles
  const int bm0 = (sw >> 4) * 128;               // 32 m-tiles, confined per XCD
  const int nt = K / BK;                         // 32 uniform

  const unsigned short* aP[4];
  const unsigned short* bP[2];
#pragma unroll
  for (int r = 0; r < 4; r++) {
    int idx = r * 256 + tid;
    int row = idx >> 3;
    int col = ((idx & 7) ^ (row & 7)) * 8;
    aP[r] = A + (size_t)(bm0 + row) * K + col;
  }
#pragma unroll
  for (int r = 0; r < 2; r++) {
    int idx = r * 256 + tid;
    int row = idx >> 3;
    int col = ((idx & 7) ^ (row & 7)) * 8;
    bP[r] = BT + (size_t)(bn0 + row) * K + col;
  }

  f32x4 acc[4][2] = {};

  auto stage = [&](int buf) {
#pragma unroll
    for (int r = 0; r < 4; r++) {
      g2l16(aP[r], &sA[buf * ASZ + (r * 256 + tid) * 8]);
      aP[r] += BK;
    }
#pragma unroll
    for (int r = 0; r < 2; r++) {
      g2l16(bP[r], &sB[buf * BSZ + (r * 256 + tid) * 8]);
      bP[r] += BK;
    }
  };

  auto compute = [&](int buf) {
    const unsigned short* bA = &sA[buf * ASZ];
    const unsigned short* bB = &sB[buf * BSZ];
    bf16x8 af[2][4], bfr[2][2];
#pragma unroll
    for (int h = 0; h < 2; h++) {
#pragma unroll
      for (int i = 0; i < 4; i++) {
        int R = wm * 64 + i * 16 + l16;
        af[h][i] = *(const bf16x8*)&bA[R * BK + (((h * 4 + quad) ^ (R & 7)) * 8)];
      }
#pragma unroll
      for (int j = 0; j < 2; j++) {
        int R = wn * 32 + j * 16 + l16;
        bfr[h][j] = *(const bf16x8*)&bB[R * BK + (((h * 4 + quad) ^ (R & 7)) * 8)];
      }
    }
    __builtin_amdgcn_s_setprio(1);
#pragma unroll
    for (int h = 0; h < 2; h++)
#pragma unroll
      for (int i = 0; i < 4; i++)
#pragma unroll
        for (int j = 0; j < 2; j++)
          acc[i][j] = __builtin_amdgcn_mfma_f32_16x16x32_bf16(af[h][i], bfr[h][j], acc[i][j], 0, 0, 0);
    __builtin_amdgcn_s_setprio(0);
  };

  stage(0);
  int cur = 0;
  for (int t = 0; t < nt; t++) {
    if (t + 1 < nt) {
      stage(cur ^ 1);
      // 6 loads per stage: wait for stage(t) (oldest 6); stage(t+1) in flight
      asm volatile("s_waitcnt vmcnt(6)" ::: "memory");
    } else {
      asm volatile("s_waitcnt vmcnt(0)" ::: "memory");
    }
    __builtin_amdgcn_s_barrier();
    compute(cur);
    __builtin_amdgcn_s_barrier();
    cur ^= 1;
  }

#pragma unroll
  for (int i = 0; i < 4; i++) {
#pragma unroll
    for (int j = 0; j < 2; j++) {
      int col = bn0 + wn * 32 + j * 16 + l16;
#pragma unroll
      for (int r = 0; r < 4; r++) {
        int row = bm0 + wm * 64 + i * 16 + quad * 4 + r;
        out[(size_t)row * N + col] = acc[i][j][r] + cbias[col];
      }
    }
  }
}

// ---- launch ---------------------------------------------------------------

extern "C" void kernel_launch(void* const* d_in, const int* in_sizes, int n_in,
                              void* d_out, int out_size, void* d_ws, size_t ws_size,
                              hipStream_t stream) {
  (void)in_sizes; (void)n_in; (void)out_size; (void)ws_size;
  const float* x   = (const float*)d_in[0];
  const float* lns = (const float*)d_in[1];
  const float* w   = (const float*)d_in[2];
  const float* sb  = (const float*)d_in[3];
  const float* pw  = (const float*)d_in[4];
  const float* pb  = (const float*)d_in[5];
  float* out = (float*)d_out;

  char* p = (char*)d_ws;
  unsigned char*  wf8   = (unsigned char*)p;  p += (size_t)SEQ * SEQ;        // 16 MB
  unsigned char*  gf8T  = (unsigned char*)p;  p += (size_t)DH * SEQ;         //  8 MB
  unsigned short* projT = (unsigned short*)p; p += (size_t)DOUT * DH * 2;    //  4 MB
  unsigned short* Pbuf  = (unsigned short*)p; p += (size_t)SEQ * DH * 2;     // 16 MB
  float* mv = (float*)p; p += (size_t)SEQ * 4;
  float* rv = (float*)p; p += (size_t)SEQ * 4;

  // prep: stats first (gates norm), then one fused kernel for everything else
  ln_stats<<<SEQ, 256, 0, stream>>>(x, mv, rv);
  prep2<<<2048 + 4096 + 512, 256, 0, stream>>>(x, mv, rv, lns, gf8T, w, wf8, pw, projT);

  // GEMM1 (fp8): gate2 = tril(w) @ gate  (M=4096, N=2048, K=4096, causal)
  gemm_f8<<<1024, 256, 0, stream>>>(wf8, gf8T, x, sb, Pbuf);

  // GEMM2 (bf16): out = P @ proj_w + proj_b  (M=4096, N=1024, K=2048)
  // 128x64 tiles BK=64, 512 blocks (2/CU), counted vmcnt(6), setprio.
  gemm_bf<<<512, 256, 0, stream>>>(Pbuf, projT, pb, out, DOUT, DH);
}